// Round 27
// baseline (156.804 us; speedup 1.0000x reference)
//
#include <hip/hip_runtime.h>
#include <hip/hip_bf16.h>

#define H_DIM 768
#define S_LEN 128
#define NT6 6        // 768 / 128 K-tiles
#define MROWS 8192   // fixed row stride of the transposed granule arrays

typedef __attribute__((ext_vector_type(4))) int int4v;
typedef __attribute__((ext_vector_type(2))) int int2v;

__device__ __forceinline__ void gload_lds16(const void* g, void* l) {
  __builtin_amdgcn_global_load_lds(
      (const __attribute__((address_space(1))) unsigned int*)g,
      (__attribute__((address_space(3))) unsigned int*)l, 16, 0, 0);
}

// ---------------- K0: per-seq ballot scan -> seq-local compact index + counts ----------------
__global__ __launch_bounds__(128) void prep_kernel(
    const int* __restrict__ mask1, const int* __restrict__ mask2,
    int* __restrict__ dest, int* __restrict__ cnts) {
  const int sq = blockIdx.x;  // 0..127 (0..63 x1, 64..127 x2)
  const int* mask = (sq < 64) ? (mask1 + sq * S_LEN) : (mask2 + (sq - 64) * S_LEN);
  const int tid = threadIdx.x;
  const int lane = tid & 63, wv = tid >> 6;
  const int m = mask[tid] ? 1 : 0;
  const unsigned long long bal = __ballot(m);
  const int pre = __popcll(bal & ((1ull << lane) - 1ull));
  __shared__ int wsum[2];
  if (lane == 0) wsum[wv] = __popcll(bal);
  __syncthreads();
  const int base = (wv == 1) ? wsum[0] : 0;
  dest[sq * S_LEN + tid] = m ? (base + pre) : -1;
  if (tid == 0) cnts[sq] = wsum[0] + wsum[1];
}

// ---------------- K1: parallel offsets + granule bitmasks ----------------
__global__ __launch_bounds__(512) void scan_kernel(
    const int* __restrict__ cnts, int* __restrict__ off1, int* __restrict__ off2,
    unsigned* __restrict__ vbitsM, unsigned* __restrict__ vbitsN,
    int* __restrict__ dims) {
  __shared__ int so1[65], so2[65];
  const int tid = threadIdx.x;
  const int lane = tid & 63, wv = tid >> 6;
  if (tid < 128) {  // wave 0 -> side M, wave 1 -> side N
    const int* cb = (wv == 0) ? cnts : (cnts + 64);
    const int np = (cb[lane] + 15) & ~15;
    int inc = np;
#pragma unroll
    for (int o = 1; o < 64; o <<= 1) {
      const int t = __shfl_up(inc, o);
      if (lane >= o) inc += t;
    }
    int* so = wv ? so2 : so1;
    so[lane] = inc - np;
    if (lane == 63) so[64] = inc;
  }
  __syncthreads();
  const int Mtot = so1[64], Ntot = so2[64];
  if (tid == 0) {
    const int Mpad = (Mtot + 127) & ~127, Npad = (Ntot + 127) & ~127;
    dims[0] = Mpad; dims[1] = Npad; dims[2] = Mpad >> 7; dims[3] = Npad >> 7;
  }
  if (tid < 65) { off1[tid] = so1[tid]; off2[tid] = so2[tid]; }
  unsigned bm = 0, bn = 0;
  const int r0 = tid * 16;
  if (r0 < Mtot) {
    int s = 0;
    while (so1[s + 1] <= r0) ++s;
    const int b0 = so1[s], nv = cnts[s];
#pragma unroll
    for (int k = 0; k < 16; ++k)
      if (r0 + k - b0 < nv) bm |= (1u << k);
  }
  if (r0 < Ntot) {
    int s = 0;
    while (so2[s + 1] <= r0) ++s;
    const int b0 = so2[s], nv = cnts[64 + s];
#pragma unroll
    for (int k = 0; k < 16; ++k)
      if (r0 + k - b0 < nv) bn |= (1u << k);
  }
  vbitsM[tid] = bm;
  vbitsN[tid] = bn;
}

// ---------------- K2: normalize + per-token INT8 quantize; zero pad rows + scales ----------------
// q_i = rint(x_i * 127 / maxabs);  scale s = maxabs/(127*norm) so s*q ~= x/norm.
__global__ __launch_bounds__(256) void normzero_kernel(
    const float* __restrict__ x1, const float* __restrict__ x2,
    const int* __restrict__ dest, const int* __restrict__ off1,
    const int* __restrict__ off2,
    const unsigned* __restrict__ vbitsM, const unsigned* __restrict__ vbitsN,
    const int* __restrict__ dims,
    signed char* __restrict__ xq1, signed char* __restrict__ xq2,
    float* __restrict__ sc1, float* __restrict__ sc2) {
  const int gid = blockIdx.x;
  const int tid = threadIdx.x;
  if (gid >= 16384) {  // pad-row zero duty
    const int row = gid - 16384;
    const bool zM = (row < dims[0]) && !((vbitsM[row >> 4] >> (row & 15)) & 1u);
    const bool zN = (row < dims[1]) && !((vbitsN[row >> 4] >> (row & 15)) & 1u);
    if (tid < 96) {  // 96 x 8B = 768 B row
      const int2v z = (int2v){0, 0};
      if (zM) reinterpret_cast<int2v*>(xq1 + (size_t)row * H_DIM)[tid] = z;
      if (zN) reinterpret_cast<int2v*>(xq2 + (size_t)row * H_DIM)[tid] = z;
    }
    if (tid == 0) {
      if (zM) sc1[row] = 0.f;
      if (zN) sc2[row] = 0.f;
    }
    return;
  }
  const int sg = gid >> 7, tok = gid & 127;
  const int d = dest[sg * S_LEN + tok];
  if (d < 0) return;  // block-uniform exit for masked tokens
  const bool is1 = (gid < 8192);
  const float* row = is1 ? (x1 + (size_t)gid * H_DIM)
                         : (x2 + (size_t)(gid - 8192) * H_DIM);
  const int grow = (is1 ? off1[sg] : off2[sg - 64]) + d;
  signed char* xq = is1 ? xq1 : xq2;
  float* scp = is1 ? sc1 : sc2;
  float4 v = make_float4(0.f, 0.f, 0.f, 0.f);
  float ss = 0.f, ma = 0.f;
  if (tid < 192) {
    v = reinterpret_cast<const float4*>(row)[tid];
    ss = v.x * v.x + v.y * v.y + v.z * v.z + v.w * v.w;
    ma = fmaxf(fmaxf(fabsf(v.x), fabsf(v.y)), fmaxf(fabsf(v.z), fabsf(v.w)));
  }
#pragma unroll
  for (int o = 32; o > 0; o >>= 1) {
    ss += __shfl_down(ss, o);
    ma = fmaxf(ma, __shfl_down(ma, o));
  }
  __shared__ float ws[4], wmx[4];
  if ((tid & 63) == 0) { ws[tid >> 6] = ss; wmx[tid >> 6] = ma; }
  __syncthreads();
  const float norm = sqrtf(ws[0] + ws[1] + ws[2] + ws[3]);
  const float maxab = fmaxf(fmaxf(wmx[0], wmx[1]), fmaxf(wmx[2], wmx[3]));
  const float qs = 127.0f / maxab;
  if (tid < 192) {
    const int q0 = __float2int_rn(v.x * qs);
    const int q1 = __float2int_rn(v.y * qs);
    const int q2 = __float2int_rn(v.z * qs);
    const int q3 = __float2int_rn(v.w * qs);
    const unsigned p = (q0 & 0xff) | ((q1 & 0xff) << 8) | ((q2 & 0xff) << 16) |
                       ((unsigned)(q3 & 0xff) << 24);
    reinterpret_cast<unsigned*>(xq + (size_t)grow * H_DIM)[tid] = p;
  }
  if (tid == 0) scp[grow] = maxab / (127.0f * norm);
}

// ---------------- K3: INT8 dense GEMM, BK=128, 6 drain-steps, 5 blocks/CU ----------------
// R26 body with __launch_bounds__(256,5): 32 KB LDS x 5 = 160 KB (full LDS),
// 20 waves/CU — 25% more independent stage streams to hide the per-step
// vmcnt(0) drains. Regs 64 VGPR + 64 AGPR = 128, cap 409 (no spill possible).
__global__ __launch_bounds__(256, 5) void gemm_kernel(
    const signed char* __restrict__ xq1, const signed char* __restrict__ xq2,
    const float* __restrict__ sc1, const float* __restrict__ sc2,
    const unsigned* __restrict__ vbitsM, const unsigned* __restrict__ vbitsN,
    const int* __restrict__ dims,
    float* __restrict__ rowgranT, float* __restrict__ colgranT) {
  __shared__ __align__(16) signed char Al[128 * 128];  // 16 KB
  __shared__ __align__(16) signed char Bl[128 * 128];  // 16 KB
  const int Mt = dims[2], Nt = dims[3];
  const int bid = blockIdx.x;
  const int band = bid & 7;        // XCD id under round-robin dispatch
  const int idx = bid >> 3;
  const int Ntb = (Nt + 7) >> 3;
  const int mt = idx / Ntb;
  const int nt = band * Ntb + (idx - mt * Ntb);
  if (mt >= Mt || nt >= Nt) return;
  const int tid = threadIdx.x;
  const int lane = tid & 63, w = tid >> 6;
  const int wm = w >> 1, wn = w & 1;
  const int g = lane >> 4, rl = lane & 15;
  const signed char* A0 = xq1 + (size_t)mt * 128 * H_DIM;
  const signed char* B0 = xq2 + (size_t)nt * 128 * H_DIM;

  int4v acc[4][4];  // row = wm*64+i*16+g*4+r, col = wn*64+j*16+rl
#pragma unroll
  for (int i = 0; i < 4; ++i)
#pragma unroll
    for (int j = 0; j < 4; ++j) acc[i][j] = (int4v){0, 0, 0, 0};

  for (int t = 0; t < NT6; ++t) {
    __syncthreads();
    const int k0 = t * 128;
    // 1024 16B-chunks per operand, 4 each per thread. Linear LDS dest,
    // inverse-swizzled global source chunk (rule 21; involution (row&7)).
#pragma unroll
    for (int q = 0; q < 4; ++q) {
      const int s = q * 256 + tid;
      const int row = s >> 3;  // 8 chunks (128 B) per row
      const int cb = (s & 7) ^ (row & 7);
      gload_lds16(A0 + (size_t)row * H_DIM + k0 + cb * 16, Al + s * 16);
      gload_lds16(B0 + (size_t)row * H_DIM + k0 + cb * 16, Bl + s * 16);
    }
    __syncthreads();  // drains vmcnt(0)
#pragma unroll
    for (int kh = 0; kh < 2; ++kh) {
      const int slot = (kh * 4 + g) ^ (rl & 7);  // frag row&7 == rl&7
      int4v av[4], bv[4];
#pragma unroll
      for (int i = 0; i < 4; ++i)
        av[i] = *reinterpret_cast<const int4v*>(
            &Al[(wm * 64 + i * 16 + rl) * 128 + slot * 16]);
#pragma unroll
      for (int j = 0; j < 4; ++j)
        bv[j] = *reinterpret_cast<const int4v*>(
            &Bl[(wn * 64 + j * 16 + rl) * 128 + slot * 16]);
      __builtin_amdgcn_s_setprio(1);
#pragma unroll
      for (int i = 0; i < 4; ++i)
#pragma unroll
        for (int j = 0; j < 4; ++j)
          acc[i][j] = __builtin_amdgcn_mfma_i32_16x16x64_i8(
              av[i], bv[j], acc[i][j], 0, 0, 0);
      __builtin_amdgcn_s_setprio(0);
    }
  }

  // ---- dequant scales (L2-hot) ----
  float scB[4], scA[4][4];
#pragma unroll
  for (int j = 0; j < 4; ++j) scB[j] = sc2[nt * 128 + wn * 64 + j * 16 + rl];
#pragma unroll
  for (int i = 0; i < 4; ++i)
#pragma unroll
    for (int r = 0; r < 4; ++r)
      scA[i][r] = sc1[mt * 128 + wm * 64 + i * 16 + g * 4 + r];

  unsigned bM[4], bN[4];
#pragma unroll
  for (int i = 0; i < 4; ++i) bM[i] = vbitsM[mt * 8 + wm * 4 + i];
#pragma unroll
  for (int j = 0; j < 4; ++j) bN[j] = vbitsN[nt * 8 + wn * 4 + j];

  // per-row max over each col-granule (valid-col bit per lane)
#pragma unroll
  for (int i = 0; i < 4; ++i)
#pragma unroll
    for (int j = 0; j < 4; ++j) {
      const unsigned cvb = bN[j];
#pragma unroll
      for (int r = 0; r < 4; ++r) {
        const float val = (float)acc[i][j][r] * scA[i][r] * scB[j];
        float pm = ((cvb >> rl) & 1u) ? val : -INFINITY;
#pragma unroll
        for (int o = 1; o < 16; o <<= 1) pm = fmaxf(pm, __shfl_xor(pm, o));
        if (rl == 0)
          rowgranT[(size_t)(nt * 8 + wn * 4 + j) * MROWS + mt * 128 + wm * 64 +
                   i * 16 + g * 4 + r] = pm;
      }
    }
  // per-col max over each row-granule (valid-row bit per (g,r))
#pragma unroll
  for (int i = 0; i < 4; ++i)
#pragma unroll
    for (int j = 0; j < 4; ++j) {
      const unsigned rvb = bM[i];
      float cm = -INFINITY;
#pragma unroll
      for (int r = 0; r < 4; ++r)
        if ((rvb >> (g * 4 + r)) & 1u)
          cm = fmaxf(cm, (float)acc[i][j][r] * scA[i][r] * scB[j]);
      cm = fmaxf(cm, __shfl_xor(cm, 16));
      cm = fmaxf(cm, __shfl_xor(cm, 32));
      if (g == 0)
        colgranT[(size_t)(mt * 8 + wm * 4 + i) * MROWS + nt * 128 + wn * 64 +
                 j * 16 + rl] = cm;
    }
}

// ---------------- K4: final reduce — one block per (a,b), coalesced reads ----------------
__global__ __launch_bounds__(128) void reduce_kernel(
    const float* __restrict__ rowgranT, const float* __restrict__ colgranT,
    const int* __restrict__ cnts, const int* __restrict__ off1,
    const int* __restrict__ off2, float* __restrict__ out) {
  const int a = blockIdx.x >> 6, b = blockIdx.x & 63;
  const int n1 = cnts[a], n2 = cnts[64 + b];
  const int o1 = off1[a], o2 = off2[b];
  const int g2s = o2 >> 4, g2n = (n2 + 15) >> 4;
  const int g1s = o1 >> 4, g1n = (n1 + 15) >> 4;
  const int tid = threadIdx.x;
  float v1 = 0.f, v2 = 0.f;
  if (tid < n1) {
    float mx = -INFINITY;
    for (int q = 0; q < g2n; ++q)
      mx = fmaxf(mx, rowgranT[(size_t)(g2s + q) * MROWS + o1 + tid]);
    v1 = mx;
  }
  if (tid < n2) {
    float mx = -INFINITY;
    for (int q = 0; q < g1n; ++q)
      mx = fmaxf(mx, colgranT[(size_t)(g1s + q) * MROWS + o2 + tid]);
    v2 = mx;
  }
#pragma unroll
  for (int o = 32; o > 0; o >>= 1) {
    v1 += __shfl_down(v1, o);
    v2 += __shfl_down(v2, o);
  }
  __shared__ float s1[2], s2[2];
  if ((tid & 63) == 0) { s1[tid >> 6] = v1; s2[tid >> 6] = v2; }
  __syncthreads();
  if (tid == 0)
    out[a * 64 + b] =
        0.5f * ((s1[0] + s1[1]) / (float)n1 + (s2[0] + s2[1]) / (float)n2);
}

extern "C" void kernel_launch(void* const* d_in, const int* in_sizes, int n_in,
                              void* d_out, int out_size, void* d_ws, size_t ws_size,
                              hipStream_t stream) {
  const float* x1 = (const float*)d_in[0];
  const int* mask1 = (const int*)d_in[1];
  const float* x2 = (const float*)d_in[2];
  const int* mask2 = (const int*)d_in[3];
  float* out = (float*)d_out;

  // workspace layout (~45 MB)
  signed char* xq1 = (signed char*)d_ws;                   // 8192*768 i8
  signed char* xq2 = xq1 + (size_t)8192 * H_DIM;           // 8192*768 i8
  float* rowgranT = (float*)(xq2 + (size_t)8192 * H_DIM);  // [512][8192] f32
  float* colgranT = rowgranT + (size_t)512 * MROWS;        // [512][8192] f32
  float* sc1 = colgranT + (size_t)512 * MROWS;             // 8192 f32
  float* sc2 = sc1 + 8192;                                 // 8192 f32
  int* dest = (int*)(sc2 + 8192);                          // 128*128
  int* cnts = dest + 128 * S_LEN;                          // 128
  int* off1 = cnts + 128;                                  // 65
  int* off2 = off1 + 65;                                   // 65
  unsigned* vbitsM = (unsigned*)(off2 + 65);               // 512
  unsigned* vbitsN = vbitsM + 512;                         // 512
  int* dims = (int*)(vbitsN + 512);                        // 4

  prep_kernel<<<128, 128, 0, stream>>>(mask1, mask2, dest, cnts);
  scan_kernel<<<1, 512, 0, stream>>>(cnts, off1, off2, vbitsM, vbitsN, dims);
  normzero_kernel<<<24576, 256, 0, stream>>>(x1, x2, dest, off1, off2, vbitsM,
                                             vbitsN, dims, xq1, xq2, sc1, sc2);
  gemm_kernel<<<4096, 256, 0, stream>>>(xq1, xq2, sc1, sc2, vbitsM, vbitsN,
                                        dims, rowgranT, colgranT);
  reduce_kernel<<<4096, 128, 0, stream>>>(rowgranT, colgranT, cnts, off1, off2,
                                          out);
}

// Round 28
// 80.977 us; speedup vs baseline: 1.9364x; 1.9364x over previous
//
#include <hip/hip_runtime.h>
#include <hip/hip_bf16.h>

#define H_DIM 768
#define S_LEN 128
#define NT6 6        // 768 / 128 K-tiles
#define MROWS 8192   // fixed row stride of the transposed granule arrays

typedef __attribute__((ext_vector_type(4))) int int4v;
typedef __attribute__((ext_vector_type(2))) int int2v;

__device__ __forceinline__ void gload_lds16(const void* g, void* l) {
  __builtin_amdgcn_global_load_lds(
      (const __attribute__((address_space(1))) unsigned int*)g,
      (__attribute__((address_space(3))) unsigned int*)l, 16, 0, 0);
}

// ---------------- K0: per-seq ballot scan -> seq-local compact index + counts ----------------
__global__ __launch_bounds__(128) void prep_kernel(
    const int* __restrict__ mask1, const int* __restrict__ mask2,
    int* __restrict__ dest, int* __restrict__ cnts) {
  const int sq = blockIdx.x;  // 0..127 (0..63 x1, 64..127 x2)
  const int* mask = (sq < 64) ? (mask1 + sq * S_LEN) : (mask2 + (sq - 64) * S_LEN);
  const int tid = threadIdx.x;
  const int lane = tid & 63, wv = tid >> 6;
  const int m = mask[tid] ? 1 : 0;
  const unsigned long long bal = __ballot(m);
  const int pre = __popcll(bal & ((1ull << lane) - 1ull));
  __shared__ int wsum[2];
  if (lane == 0) wsum[wv] = __popcll(bal);
  __syncthreads();
  const int base = (wv == 1) ? wsum[0] : 0;
  dest[sq * S_LEN + tid] = m ? (base + pre) : -1;
  if (tid == 0) cnts[sq] = wsum[0] + wsum[1];
}

// ---------------- K1: parallel offsets + granule bitmasks ----------------
__global__ __launch_bounds__(512) void scan_kernel(
    const int* __restrict__ cnts, int* __restrict__ off1, int* __restrict__ off2,
    unsigned* __restrict__ vbitsM, unsigned* __restrict__ vbitsN,
    int* __restrict__ dims) {
  __shared__ int so1[65], so2[65];
  const int tid = threadIdx.x;
  const int lane = tid & 63, wv = tid >> 6;
  if (tid < 128) {  // wave 0 -> side M, wave 1 -> side N
    const int* cb = (wv == 0) ? cnts : (cnts + 64);
    const int np = (cb[lane] + 15) & ~15;
    int inc = np;
#pragma unroll
    for (int o = 1; o < 64; o <<= 1) {
      const int t = __shfl_up(inc, o);
      if (lane >= o) inc += t;
    }
    int* so = wv ? so2 : so1;
    so[lane] = inc - np;
    if (lane == 63) so[64] = inc;
  }
  __syncthreads();
  const int Mtot = so1[64], Ntot = so2[64];
  if (tid == 0) {
    const int Mpad = (Mtot + 127) & ~127, Npad = (Ntot + 127) & ~127;
    dims[0] = Mpad; dims[1] = Npad; dims[2] = Mpad >> 7; dims[3] = Npad >> 7;
  }
  if (tid < 65) { off1[tid] = so1[tid]; off2[tid] = so2[tid]; }
  unsigned bm = 0, bn = 0;
  const int r0 = tid * 16;
  if (r0 < Mtot) {
    int s = 0;
    while (so1[s + 1] <= r0) ++s;
    const int b0 = so1[s], nv = cnts[s];
#pragma unroll
    for (int k = 0; k < 16; ++k)
      if (r0 + k - b0 < nv) bm |= (1u << k);
  }
  if (r0 < Ntot) {
    int s = 0;
    while (so2[s + 1] <= r0) ++s;
    const int b0 = so2[s], nv = cnts[64 + s];
#pragma unroll
    for (int k = 0; k < 16; ++k)
      if (r0 + k - b0 < nv) bn |= (1u << k);
  }
  vbitsM[tid] = bm;
  vbitsN[tid] = bn;
}

// ---------------- K2: normalize + per-token INT8 quantize; zero pad rows + scales ----------------
// q_i = rint(x_i * 127 / maxabs);  scale s = maxabs/(127*norm) so s*q ~= x/norm.
__global__ __launch_bounds__(256) void normzero_kernel(
    const float* __restrict__ x1, const float* __restrict__ x2,
    const int* __restrict__ dest, const int* __restrict__ off1,
    const int* __restrict__ off2,
    const unsigned* __restrict__ vbitsM, const unsigned* __restrict__ vbitsN,
    const int* __restrict__ dims,
    signed char* __restrict__ xq1, signed char* __restrict__ xq2,
    float* __restrict__ sc1, float* __restrict__ sc2) {
  const int gid = blockIdx.x;
  const int tid = threadIdx.x;
  if (gid >= 16384) {  // pad-row zero duty
    const int row = gid - 16384;
    const bool zM = (row < dims[0]) && !((vbitsM[row >> 4] >> (row & 15)) & 1u);
    const bool zN = (row < dims[1]) && !((vbitsN[row >> 4] >> (row & 15)) & 1u);
    if (tid < 96) {  // 96 x 8B = 768 B row
      const int2v z = (int2v){0, 0};
      if (zM) reinterpret_cast<int2v*>(xq1 + (size_t)row * H_DIM)[tid] = z;
      if (zN) reinterpret_cast<int2v*>(xq2 + (size_t)row * H_DIM)[tid] = z;
    }
    if (tid == 0) {
      if (zM) sc1[row] = 0.f;
      if (zN) sc2[row] = 0.f;
    }
    return;
  }
  const int sg = gid >> 7, tok = gid & 127;
  const int d = dest[sg * S_LEN + tok];
  if (d < 0) return;  // block-uniform exit for masked tokens
  const bool is1 = (gid < 8192);
  const float* row = is1 ? (x1 + (size_t)gid * H_DIM)
                         : (x2 + (size_t)(gid - 8192) * H_DIM);
  const int grow = (is1 ? off1[sg] : off2[sg - 64]) + d;
  signed char* xq = is1 ? xq1 : xq2;
  float* scp = is1 ? sc1 : sc2;
  float4 v = make_float4(0.f, 0.f, 0.f, 0.f);
  float ss = 0.f, ma = 0.f;
  if (tid < 192) {
    v = reinterpret_cast<const float4*>(row)[tid];
    ss = v.x * v.x + v.y * v.y + v.z * v.z + v.w * v.w;
    ma = fmaxf(fmaxf(fabsf(v.x), fabsf(v.y)), fmaxf(fabsf(v.z), fabsf(v.w)));
  }
#pragma unroll
  for (int o = 32; o > 0; o >>= 1) {
    ss += __shfl_down(ss, o);
    ma = fmaxf(ma, __shfl_down(ma, o));
  }
  __shared__ float ws[4], wmx[4];
  if ((tid & 63) == 0) { ws[tid >> 6] = ss; wmx[tid >> 6] = ma; }
  __syncthreads();
  const float norm = sqrtf(ws[0] + ws[1] + ws[2] + ws[3]);
  const float maxab = fmaxf(fmaxf(wmx[0], wmx[1]), fmaxf(wmx[2], wmx[3]));
  const float qs = 127.0f / maxab;
  if (tid < 192) {
    const int q0 = __float2int_rn(v.x * qs);
    const int q1 = __float2int_rn(v.y * qs);
    const int q2 = __float2int_rn(v.z * qs);
    const int q3 = __float2int_rn(v.w * qs);
    const unsigned p = (q0 & 0xff) | ((q1 & 0xff) << 8) | ((q2 & 0xff) << 16) |
                       ((unsigned)(q3 & 0xff) << 24);
    reinterpret_cast<unsigned*>(xq + (size_t)grow * H_DIM)[tid] = p;
  }
  if (tid == 0) scp[grow] = maxab / (127.0f * norm);
}

// ---------------- K3: INT8 dense GEMM, BK=128, 6 drain-steps, 4 blocks/CU ----------------
// R26 config (measured best: gemm 47.5 us, 0 conflicts, 0 spill).
// (256,4): 4 blocks x 128 regs = 512 = full per-SIMD pool; 4 x 32 KB LDS.
// (256,5) is impossible: 5 x 128 = 640 > 512 -> R27's catastrophic spill.
__global__ __launch_bounds__(256, 4) void gemm_kernel(
    const signed char* __restrict__ xq1, const signed char* __restrict__ xq2,
    const float* __restrict__ sc1, const float* __restrict__ sc2,
    const unsigned* __restrict__ vbitsM, const unsigned* __restrict__ vbitsN,
    const int* __restrict__ dims,
    float* __restrict__ rowgranT, float* __restrict__ colgranT) {
  __shared__ __align__(16) signed char Al[128 * 128];  // 16 KB
  __shared__ __align__(16) signed char Bl[128 * 128];  // 16 KB
  const int Mt = dims[2], Nt = dims[3];
  const int bid = blockIdx.x;
  const int band = bid & 7;        // XCD id under round-robin dispatch
  const int idx = bid >> 3;
  const int Ntb = (Nt + 7) >> 3;
  const int mt = idx / Ntb;
  const int nt = band * Ntb + (idx - mt * Ntb);
  if (mt >= Mt || nt >= Nt) return;
  const int tid = threadIdx.x;
  const int lane = tid & 63, w = tid >> 6;
  const int wm = w >> 1, wn = w & 1;
  const int g = lane >> 4, rl = lane & 15;
  const signed char* A0 = xq1 + (size_t)mt * 128 * H_DIM;
  const signed char* B0 = xq2 + (size_t)nt * 128 * H_DIM;

  int4v acc[4][4];  // row = wm*64+i*16+g*4+r, col = wn*64+j*16+rl
#pragma unroll
  for (int i = 0; i < 4; ++i)
#pragma unroll
    for (int j = 0; j < 4; ++j) acc[i][j] = (int4v){0, 0, 0, 0};

  for (int t = 0; t < NT6; ++t) {
    __syncthreads();
    const int k0 = t * 128;
    // 1024 16B-chunks per operand, 4 each per thread. Linear LDS dest,
    // inverse-swizzled global source chunk (rule 21; involution (row&7)).
#pragma unroll
    for (int q = 0; q < 4; ++q) {
      const int s = q * 256 + tid;
      const int row = s >> 3;  // 8 chunks (128 B) per row
      const int cb = (s & 7) ^ (row & 7);
      gload_lds16(A0 + (size_t)row * H_DIM + k0 + cb * 16, Al + s * 16);
      gload_lds16(B0 + (size_t)row * H_DIM + k0 + cb * 16, Bl + s * 16);
    }
    __syncthreads();  // drains vmcnt(0)
#pragma unroll
    for (int kh = 0; kh < 2; ++kh) {
      const int slot = (kh * 4 + g) ^ (rl & 7);  // frag row&7 == rl&7
      int4v av[4], bv[4];
#pragma unroll
      for (int i = 0; i < 4; ++i)
        av[i] = *reinterpret_cast<const int4v*>(
            &Al[(wm * 64 + i * 16 + rl) * 128 + slot * 16]);
#pragma unroll
      for (int j = 0; j < 4; ++j)
        bv[j] = *reinterpret_cast<const int4v*>(
            &Bl[(wn * 64 + j * 16 + rl) * 128 + slot * 16]);
      __builtin_amdgcn_s_setprio(1);
#pragma unroll
      for (int i = 0; i < 4; ++i)
#pragma unroll
        for (int j = 0; j < 4; ++j)
          acc[i][j] = __builtin_amdgcn_mfma_i32_16x16x64_i8(
              av[i], bv[j], acc[i][j], 0, 0, 0);
      __builtin_amdgcn_s_setprio(0);
    }
  }

  // ---- dequant scales (L2-hot) ----
  float scB[4], scA[4][4];
#pragma unroll
  for (int j = 0; j < 4; ++j) scB[j] = sc2[nt * 128 + wn * 64 + j * 16 + rl];
#pragma unroll
  for (int i = 0; i < 4; ++i)
#pragma unroll
    for (int r = 0; r < 4; ++r)
      scA[i][r] = sc1[mt * 128 + wm * 64 + i * 16 + g * 4 + r];

  unsigned bM[4], bN[4];
#pragma unroll
  for (int i = 0; i < 4; ++i) bM[i] = vbitsM[mt * 8 + wm * 4 + i];
#pragma unroll
  for (int j = 0; j < 4; ++j) bN[j] = vbitsN[nt * 8 + wn * 4 + j];

  // per-row max over each col-granule (valid-col bit per lane)
#pragma unroll
  for (int i = 0; i < 4; ++i)
#pragma unroll
    for (int j = 0; j < 4; ++j) {
      const unsigned cvb = bN[j];
#pragma unroll
      for (int r = 0; r < 4; ++r) {
        const float val = (float)acc[i][j][r] * scA[i][r] * scB[j];
        float pm = ((cvb >> rl) & 1u) ? val : -INFINITY;
#pragma unroll
        for (int o = 1; o < 16; o <<= 1) pm = fmaxf(pm, __shfl_xor(pm, o));
        if (rl == 0)
          rowgranT[(size_t)(nt * 8 + wn * 4 + j) * MROWS + mt * 128 + wm * 64 +
                   i * 16 + g * 4 + r] = pm;
      }
    }
  // per-col max over each row-granule (valid-row bit per (g,r))
#pragma unroll
  for (int i = 0; i < 4; ++i)
#pragma unroll
    for (int j = 0; j < 4; ++j) {
      const unsigned rvb = bM[i];
      float cm = -INFINITY;
#pragma unroll
      for (int r = 0; r < 4; ++r)
        if ((rvb >> (g * 4 + r)) & 1u)
          cm = fmaxf(cm, (float)acc[i][j][r] * scA[i][r] * scB[j]);
      cm = fmaxf(cm, __shfl_xor(cm, 16));
      cm = fmaxf(cm, __shfl_xor(cm, 32));
      if (g == 0)
        colgranT[(size_t)(mt * 8 + wm * 4 + i) * MROWS + nt * 128 + wn * 64 +
                 j * 16 + rl] = cm;
    }
}

// ---------------- K4: final reduce — one block per (a,b), coalesced reads ----------------
__global__ __launch_bounds__(128) void reduce_kernel(
    const float* __restrict__ rowgranT, const float* __restrict__ colgranT,
    const int* __restrict__ cnts, const int* __restrict__ off1,
    const int* __restrict__ off2, float* __restrict__ out) {
  const int a = blockIdx.x >> 6, b = blockIdx.x & 63;
  const int n1 = cnts[a], n2 = cnts[64 + b];
  const int o1 = off1[a], o2 = off2[b];
  const int g2s = o2 >> 4, g2n = (n2 + 15) >> 4;
  const int g1s = o1 >> 4, g1n = (n1 + 15) >> 4;
  const int tid = threadIdx.x;
  float v1 = 0.f, v2 = 0.f;
  if (tid < n1) {
    float mx = -INFINITY;
    for (int q = 0; q < g2n; ++q)
      mx = fmaxf(mx, rowgranT[(size_t)(g2s + q) * MROWS + o1 + tid]);
    v1 = mx;
  }
  if (tid < n2) {
    float mx = -INFINITY;
    for (int q = 0; q < g1n; ++q)
      mx = fmaxf(mx, colgranT[(size_t)(g1s + q) * MROWS + o2 + tid]);
    v2 = mx;
  }
#pragma unroll
  for (int o = 32; o > 0; o >>= 1) {
    v1 += __shfl_down(v1, o);
    v2 += __shfl_down(v2, o);
  }
  __shared__ float s1[2], s2[2];
  if ((tid & 63) == 0) { s1[tid >> 6] = v1; s2[tid >> 6] = v2; }
  __syncthreads();
  if (tid == 0)
    out[a * 64 + b] =
        0.5f * ((s1[0] + s1[1]) / (float)n1 + (s2[0] + s2[1]) / (float)n2);
}

extern "C" void kernel_launch(void* const* d_in, const int* in_sizes, int n_in,
                              void* d_out, int out_size, void* d_ws, size_t ws_size,
                              hipStream_t stream) {
  const float* x1 = (const float*)d_in[0];
  const int* mask1 = (const int*)d_in[1];
  const float* x2 = (const float*)d_in[2];
  const int* mask2 = (const int*)d_in[3];
  float* out = (float*)d_out;

  // workspace layout (~45 MB)
  signed char* xq1 = (signed char*)d_ws;                   // 8192*768 i8
  signed char* xq2 = xq1 + (size_t)8192 * H_DIM;           // 8192*768 i8
  float* rowgranT = (float*)(xq2 + (size_t)8192 * H_DIM);  // [512][8192] f32
  float* colgranT = rowgranT + (size_t)512 * MROWS;        // [512][8192] f32
  float* sc1 = colgranT + (size_t)512 * MROWS;             // 8192 f32
  float* sc2 = sc1 + 8192;                                 // 8192 f32
  int* dest = (int*)(sc2 + 8192);                          // 128*128
  int* cnts = dest + 128 * S_LEN;                          // 128
  int* off1 = cnts + 128;                                  // 65
  int* off2 = off1 + 65;                                   // 65
  unsigned* vbitsM = (unsigned*)(off2 + 65);               // 512
  unsigned* vbitsN = vbitsM + 512;                         // 512
  int* dims = (int*)(vbitsN + 512);                        // 4

  prep_kernel<<<128, 128, 0, stream>>>(mask1, mask2, dest, cnts);
  scan_kernel<<<1, 512, 0, stream>>>(cnts, off1, off2, vbitsM, vbitsN, dims);
  normzero_kernel<<<24576, 256, 0, stream>>>(x1, x2, dest, off1, off2, vbitsM,
                                             vbitsN, dims, xq1, xq2, sc1, sc2);
  gemm_kernel<<<4096, 256, 0, stream>>>(xq1, xq2, sc1, sc2, vbitsM, vbitsN,
                                        dims, rowgranT, colgranT);
  reduce_kernel<<<4096, 128, 0, stream>>>(rowgranT, colgranT, cnts, off1, off2,
                                          out);
}